// Round 3
// baseline (162.935 us; speedup 1.0000x reference)
//
#include <hip/hip_runtime.h>
#include <stdint.h>

#define NROWS 8192
#define KDIM  512
#define BM    128
#define BK    32
#define NT    (NROWS / BM)                  // 64 tiles per dim
#define NLIVE (NT * (NT + 1) / 2)           // 2080 live (upper-tri) blocks

typedef __attribute__((ext_vector_type(8))) short bf16x8;
typedef __attribute__((ext_vector_type(4))) float f32x4;

__device__ __forceinline__ unsigned short f32_to_bf16(float f) {
  union { float f; unsigned int u; } v; v.f = f;
  unsigned int u = v.u;
  u += 0x7FFFu + ((u >> 16) & 1u);   // round-to-nearest-even
  return (unsigned short)(u >> 16);
}

__device__ __forceinline__ void async_copy16(const unsigned short* g, unsigned short* l) {
  __builtin_amdgcn_global_load_lds(
      (const __attribute__((address_space(1))) unsigned int*)g,
      (__attribute__((address_space(3))) unsigned int*)l,
      16, 0, 0);
}

// Kernel 1: row-normalize fp32 -> bf16 (RNE), float4/ushort4 vectorized.
// Row 0's block also zeroes the global accumulator + completion counter.
__global__ __launch_bounds__(128) void prep_kernel(
    const float* __restrict__ src, unsigned short* __restrict__ dst,
    float* __restrict__ acc, unsigned int* __restrict__ cnt) {
  const int row = blockIdx.x;
  const int tid = threadIdx.x;
  const float4 v = ((const float4*)src)[row * 128 + tid];
  float ss = v.x * v.x + v.y * v.y + v.z * v.z + v.w * v.w;
  #pragma unroll
  for (int off = 32; off > 0; off >>= 1) ss += __shfl_down(ss, off);
  __shared__ float red[2];
  __shared__ float s_rn;
  const int lane = tid & 63, w = tid >> 6;
  if (lane == 0) red[w] = ss;
  __syncthreads();
  if (tid == 0) {
    s_rn = 1.0f / sqrtf(red[0] + red[1]);   // norms ~22.6, EPS can never fire
    if (row == 0) { *acc = 0.0f; *cnt = 0u; }
  }
  __syncthreads();
  const float rn = s_rn;
  ushort4 o;
  o.x = f32_to_bf16(v.x * rn);
  o.y = f32_to_bf16(v.y * rn);
  o.z = f32_to_bf16(v.z * rn);
  o.w = f32_to_bf16(v.w * rn);
  ((ushort4*)dst)[row * 128 + tid] = o;
}

// Kernel 2: tiled bf16 MFMA GEMM (idn @ idn^T) fused with clamp, diagonal
// masking, full reduction, and final output write (last live block finishes).
// 2D grid: linear id = bi*64+bj and 64%8==0 => XCD = bj%8. Each XCD touches
// only B-tiles with bj ≡ xcd (mod 8) (~1 MB) -> private-L2 resident across
// the whole sweep (R0 measured 31 MB fetch vs 74 MB with a 1D tri grid).
// Lower-triangle blocks exit immediately. Strictly-upper tiles weighted 2x.
// LDS k-chunk XOR swizzle: position pos in a row holds global k-chunk
// pos ^ ((row>>1)&3) -- spreads the 64B-row-stride fragment reads across all
// 8 four-bank groups (R1 measured: bank conflicts 4.26M -> 0).
__global__ __launch_bounds__(256) void sim_reduce_kernel(
    const unsigned short* __restrict__ idn, float* __restrict__ acc,
    unsigned int* __restrict__ cnt, float* __restrict__ out) {
  const int bi = blockIdx.y;
  const int bj = blockIdx.x;
  if (bj < bi) return;               // block-uniform early exit (dead block)

  __shared__ __align__(16) unsigned short As[BM * BK];
  __shared__ __align__(16) unsigned short Bs[BM * BK];
  __shared__ float red[4];

  const int tid  = threadIdx.x;      // 0..255, 4 waves
  const int lane = tid & 63;
  const int w    = tid >> 6;
  const int wr   = (w >> 1) * 64;    // wave's 64x64 quadrant
  const int wc   = (w & 1) * 64;
  const int q    = lane >> 4;        // k-chunk this lane needs (0..3)
  const int r16  = lane & 15;
  const int koff = (q ^ ((r16 >> 1) & 3)) * 8;   // swizzled read offset

  f32x4 acc_f[4][4];
  #pragma unroll
  for (int i = 0; i < 4; i++)
    #pragma unroll
    for (int j = 0; j < 4; j++)
      acc_f[i][j] = (f32x4){0.f, 0.f, 0.f, 0.f};

  // Staging: chunk c -> LDS bytes [c*16,+16) (lane-linear, as global_load_lds
  // requires). Chunk c = row c>>2, position c&3; fetches global k-chunk
  // (c&3) ^ ((c>>3)&3)  [row>>1 == c>>3].
  const int c0 = tid, c1 = tid + 256;
  const int g0 = ((c0 & 3) ^ ((c0 >> 3) & 3)) * 8;
  const int g1 = ((c1 & 3) ^ ((c1 >> 3) & 3)) * 8;
  const unsigned short* gA0 = idn + (bi * BM + (c0 >> 2)) * KDIM + g0;
  const unsigned short* gA1 = idn + (bi * BM + (c1 >> 2)) * KDIM + g1;
  const unsigned short* gB0 = idn + (bj * BM + (c0 >> 2)) * KDIM + g0;
  const unsigned short* gB1 = idn + (bj * BM + (c1 >> 2)) * KDIM + g1;
  unsigned short* lA0 = As + c0 * 8;
  unsigned short* lA1 = As + c1 * 8;
  unsigned short* lB0 = Bs + c0 * 8;
  unsigned short* lB1 = Bs + c1 * 8;

  for (int k0 = 0; k0 < KDIM; k0 += BK) {
    async_copy16(gA0 + k0, lA0);
    async_copy16(gA1 + k0, lA1);
    async_copy16(gB0 + k0, lB0);
    async_copy16(gB1 + k0, lB1);
    asm volatile("s_waitcnt vmcnt(0)" ::: "memory");
    __syncthreads();

    bf16x8 a[4], b[4];
    #pragma unroll
    for (int mi = 0; mi < 4; mi++)   // A frag: row = lane&15, k = (lane>>4)*8+j
      a[mi] = *(const bf16x8*)&As[(wr + mi * 16 + r16) * BK + koff];
    #pragma unroll
    for (int ni = 0; ni < 4; ni++)
      b[ni] = *(const bf16x8*)&Bs[(wc + ni * 16 + r16) * BK + koff];
    #pragma unroll
    for (int mi = 0; mi < 4; mi++)
      #pragma unroll
      for (int ni = 0; ni < 4; ni++)
        acc_f[mi][ni] = __builtin_amdgcn_mfma_f32_16x16x32_bf16(
            a[mi], b[ni], acc_f[mi][ni], 0, 0, 0);
    __syncthreads();
  }

  // Epilogue: clamp at zero, mask diagonal, reduce.
  // C/D layout (verified m89/m91): col = lane&15, row = (lane>>4)*4 + reg.
  float local = 0.f;
  const bool diag = (bi == bj);
  #pragma unroll
  for (int mi = 0; mi < 4; mi++)
    #pragma unroll
    for (int ni = 0; ni < 4; ni++)
      #pragma unroll
      for (int rr = 0; rr < 4; rr++) {
        const int ri = wr + mi * 16 + q * 4 + rr;
        const int ci = wc + ni * 16 + r16;
        float v = fmaxf(acc_f[mi][ni][rr], 0.f);
        if (diag && ri == ci) v = 0.f;
        local += v;
      }

  #pragma unroll
  for (int off = 32; off > 0; off >>= 1) local += __shfl_down(local, off);
  if (lane == 0) red[w] = local;
  __syncthreads();
  if (tid == 0) {
    float s = red[0] + red[1] + red[2] + red[3];
    if (!diag) s *= 2.f;             // strictly-upper tiles cover both triangles
    atomicAdd(acc, s);
    __threadfence();                 // publish before signaling completion
    const unsigned int done = atomicAdd(cnt, 1u);
    if (done == NLIVE - 1) {         // last live block: finalize
      const float tot = atomicAdd(acc, 0.0f);   // coherent read of final sum
      const float m = tot * (1.0f / ((float)NROWS * (float)NROWS));
      out[0] = m;
      out[1] = m;
    }
  }
}

extern "C" void kernel_launch(void* const* d_in, const int* in_sizes, int n_in,
                              void* d_out, int out_size, void* d_ws, size_t ws_size,
                              hipStream_t stream) {
  const float* id = (const float*)d_in[0];
  float* out = (float*)d_out;
  unsigned short* idn = (unsigned short*)d_ws;                     // 8 MB bf16
  float* acc = (float*)((char*)d_ws + (size_t)NROWS * KDIM * 2);
  unsigned int* cnt = (unsigned int*)(acc + 1);

  prep_kernel<<<NROWS, 128, 0, stream>>>(id, idn, acc, cnt);
  dim3 grid(NT, NT);
  sim_reduce_kernel<<<grid, 256, 0, stream>>>(idn, acc, cnt, out);
}

// Round 4
// 124.874 us; speedup vs baseline: 1.3048x; 1.3048x over previous
//
#include <hip/hip_runtime.h>
#include <stdint.h>

#define NROWS 8192
#define KDIM  512
#define BM    128
#define BK    32
#define NT    (NROWS / BM)                  // 64 tiles per dim

typedef __attribute__((ext_vector_type(8))) short bf16x8;
typedef __attribute__((ext_vector_type(4))) float f32x4;

__device__ __forceinline__ unsigned short f32_to_bf16(float f) {
  union { float f; unsigned int u; } v; v.f = f;
  unsigned int u = v.u;
  u += 0x7FFFu + ((u >> 16) & 1u);   // round-to-nearest-even
  return (unsigned short)(u >> 16);
}

__device__ __forceinline__ void async_copy16(const unsigned short* g, unsigned short* l) {
  __builtin_amdgcn_global_load_lds(
      (const __attribute__((address_space(1))) unsigned int*)g,
      (__attribute__((address_space(3))) unsigned int*)l,
      16, 0, 0);
}

// Kernel 1: row-normalize fp32 -> bf16 (RNE), PRE-SWIZZLED output layout.
// Within each row, global 16B k-chunk g is stored at position g ^ ((row>>1)&3)
// (permutation inside aligned 64B windows). This lets the sim kernel read
// globally in pure lane-linear order (R2 post-mortem: permuting the global
// read side broke TA request coalescing, +44 us) while the LDS tile lands
// already bank-deswizzled (R1: conflicts 4.26M -> 0).
__global__ __launch_bounds__(128) void prep_kernel(
    const float* __restrict__ src, unsigned short* __restrict__ dst,
    float* __restrict__ acc) {
  const int row = blockIdx.x;
  const int tid = threadIdx.x;
  const float4 v = ((const float4*)src)[row * 128 + tid];
  float ss = v.x * v.x + v.y * v.y + v.z * v.z + v.w * v.w;
  #pragma unroll
  for (int off = 32; off > 0; off >>= 1) ss += __shfl_down(ss, off);
  __shared__ float red[2];
  __shared__ float s_rn;
  const int lane = tid & 63, w = tid >> 6;
  if (lane == 0) red[w] = ss;
  __syncthreads();
  if (tid == 0) {
    s_rn = 1.0f / sqrtf(red[0] + red[1]);   // norms ~22.6, EPS can never fire
    if (row == 0) *acc = 0.0f;
  }
  __syncthreads();
  const float rn = s_rn;
  ushort4 o;
  o.x = f32_to_bf16(v.x * rn);
  o.y = f32_to_bf16(v.y * rn);
  o.z = f32_to_bf16(v.z * rn);
  o.w = f32_to_bf16(v.w * rn);
  // this thread produced half of 16B k-chunk cg; store at swizzled position
  const int cg   = tid >> 1;                       // chunk index 0..63
  const int xorv = (row >> 1) & 3;
  const int p    = (cg & 0x3C) | ((cg & 3) ^ xorv);
  ((ushort4*)dst)[row * 128 + p * 2 + (tid & 1)] = o;
}

// Kernel 2: tiled bf16 MFMA GEMM (idn @ idn^T) fused with clamp, diagonal
// masking, and full reduction. 2D grid: linear id = bi*64+bj, 64%8==0 =>
// XCD = bj%8 -> each XCD's B-set (~1 MB) stays L2-resident (R0/R1 A/B:
// 31 MB vs 74 MB fetch). Lower-triangle blocks exit immediately; strictly
// upper tiles weighted 2x by symmetry. Global reads are lane-linear
// (coalesced); LDS holds the pre-swizzled layout, fragment reads use koff.
__global__ __launch_bounds__(256) void sim_reduce_kernel(
    const unsigned short* __restrict__ idn, float* __restrict__ acc) {
  const int bi = blockIdx.y;
  const int bj = blockIdx.x;
  if (bj < bi) return;               // block-uniform early exit (dead block)

  __shared__ __align__(16) unsigned short As[BM * BK];
  __shared__ __align__(16) unsigned short Bs[BM * BK];
  __shared__ float red[4];

  const int tid  = threadIdx.x;      // 0..255, 4 waves
  const int lane = tid & 63;
  const int w    = tid >> 6;
  const int wr   = (w >> 1) * 64;    // wave's 64x64 quadrant
  const int wc   = (w & 1) * 64;
  const int q    = lane >> 4;        // k-chunk this lane needs (0..3)
  const int r16  = lane & 15;
  const int koff = (q ^ ((r16 >> 1) & 3)) * 8;   // deswizzle on LDS read

  f32x4 acc_f[4][4];
  #pragma unroll
  for (int i = 0; i < 4; i++)
    #pragma unroll
    for (int j = 0; j < 4; j++)
      acc_f[i][j] = (f32x4){0.f, 0.f, 0.f, 0.f};

  // Staging: chunk c -> LDS bytes [c*16,+16), lane-linear global reads.
  // Memory already holds the swizzled chunk order within each row.
  const int c0 = tid, c1 = tid + 256;
  const unsigned short* gA0 = idn + (bi * BM + (c0 >> 2)) * KDIM + (c0 & 3) * 8;
  const unsigned short* gA1 = idn + (bi * BM + (c1 >> 2)) * KDIM + (c1 & 3) * 8;
  const unsigned short* gB0 = idn + (bj * BM + (c0 >> 2)) * KDIM + (c0 & 3) * 8;
  const unsigned short* gB1 = idn + (bj * BM + (c1 >> 2)) * KDIM + (c1 & 3) * 8;
  unsigned short* lA0 = As + c0 * 8;
  unsigned short* lA1 = As + c1 * 8;
  unsigned short* lB0 = Bs + c0 * 8;
  unsigned short* lB1 = Bs + c1 * 8;

  for (int k0 = 0; k0 < KDIM; k0 += BK) {
    async_copy16(gA0 + k0, lA0);
    async_copy16(gA1 + k0, lA1);
    async_copy16(gB0 + k0, lB0);
    async_copy16(gB1 + k0, lB1);
    asm volatile("s_waitcnt vmcnt(0)" ::: "memory");
    __syncthreads();

    bf16x8 a[4], b[4];
    #pragma unroll
    for (int mi = 0; mi < 4; mi++)   // A frag: row = lane&15, k = (lane>>4)*8+j
      a[mi] = *(const bf16x8*)&As[(wr + mi * 16 + r16) * BK + koff];
    #pragma unroll
    for (int ni = 0; ni < 4; ni++)
      b[ni] = *(const bf16x8*)&Bs[(wc + ni * 16 + r16) * BK + koff];
    #pragma unroll
    for (int mi = 0; mi < 4; mi++)
      #pragma unroll
      for (int ni = 0; ni < 4; ni++)
        acc_f[mi][ni] = __builtin_amdgcn_mfma_f32_16x16x32_bf16(
            a[mi], b[ni], acc_f[mi][ni], 0, 0, 0);
    __syncthreads();
  }

  // Epilogue: clamp at zero, mask diagonal, reduce.
  // C/D layout (verified m89/m91): col = lane&15, row = (lane>>4)*4 + reg.
  float local = 0.f;
  const bool diag = (bi == bj);
  #pragma unroll
  for (int mi = 0; mi < 4; mi++)
    #pragma unroll
    for (int ni = 0; ni < 4; ni++)
      #pragma unroll
      for (int rr = 0; rr < 4; rr++) {
        const int ri = wr + mi * 16 + q * 4 + rr;
        const int ci = wc + ni * 16 + r16;
        float v = fmaxf(acc_f[mi][ni][rr], 0.f);
        if (diag && ri == ci) v = 0.f;
        local += v;
      }

  #pragma unroll
  for (int off = 32; off > 0; off >>= 1) local += __shfl_down(local, off);
  if (lane == 0) red[w] = local;
  __syncthreads();
  if (tid == 0) {
    float s = red[0] + red[1] + red[2] + red[3];
    if (!diag) s *= 2.f;             // strictly-upper tiles cover both triangles
    atomicAdd(acc, s);
  }
}

// Kernel 3: scale and write both outputs (total_loss == l_id_div, DIV_COEF=1).
__global__ void finalize_kernel(const float* __restrict__ acc, float* __restrict__ out) {
  const float m = *acc * (1.0f / ((float)NROWS * (float)NROWS));
  out[0] = m;
  out[1] = m;
}

extern "C" void kernel_launch(void* const* d_in, const int* in_sizes, int n_in,
                              void* d_out, int out_size, void* d_ws, size_t ws_size,
                              hipStream_t stream) {
  const float* id = (const float*)d_in[0];
  float* out = (float*)d_out;
  unsigned short* idn = (unsigned short*)d_ws;                     // 8 MB bf16
  float* acc = (float*)((char*)d_ws + (size_t)NROWS * KDIM * 2);

  prep_kernel<<<NROWS, 128, 0, stream>>>(id, idn, acc);
  dim3 grid(NT, NT);
  sim_reduce_kernel<<<grid, 256, 0, stream>>>(idn, acc);
  finalize_kernel<<<1, 1, 0, stream>>>(acc, out);
}